// Round 7
// baseline (726.093 us; speedup 1.0000x reference)
//
#include <hip/hip_runtime.h>
#include <hip/hip_cooperative_groups.h>

namespace cg = cooperative_groups;

#define EPS_LN 1e-5f
#define EPS_BN 1e-5f

typedef float f4 __attribute__((ext_vector_type(4)));

__device__ __forceinline__ float lrelu(float v) { return v >= 0.f ? v : 0.2f * v; }

// half-pixel 16->64 axis map: src = 0.25*o - 0.375 = (2o-3)/8
__device__ __forceinline__ void axis16(int o, int& i0, int& i1, float& f) {
  int t = 2 * o - 3;
  int q = (t >= 0) ? (t >> 3) : -1;       // floor(t/8); t >= -3 so floor=-1
  f = (float)(t - 8 * q) * 0.125f;
  i0 = q < 0 ? 0 : q;
  i1 = q + 1 > 15 ? 15 : q + 1;
}

struct P {
  const float *obj; const int *eidx; const float *vol;
  const float *W1, *as1, *ad1, *b1, *W2, *as2, *ad2, *b2, *lng, *lnb, *scp;
  const float *linW, *linb, *ct1W, *ct1b, *ct2W, *ct2b, *bng, *bnb;
  float *out, *xlg, *hct1, *h2, *psum, *pssq;
};

// ===========================================================================
// Cooperative mega-kernel: A (GAT x2 + LN + residual) -> BC (Linear+ConvT1)
// -> D (ConvT2 + BN partials) -> F (BN affine + separable trilinear + add).
// grid = 512 blocks x 256 threads; 38912 B LDS -> 4 blocks/CU max, 512
// co-resident guaranteed. All cross-phase data via ws + grid.sync().
// ===========================================================================
__global__ __launch_bounds__(256, 4) void mega(P p) {
  cg::grid_group grid = cg::this_grid();
  __shared__ __align__(16) float smem[9728];   // 38912 B, max over phases
  const int tid = threadIdx.x;
  const int bid = blockIdx.x;

  // ======================= Phase A: graph part (block 0) ===================
  if (bid == 0) {
    float* xin = smem;            // [48][9]
    float* h1  = smem + 432;      // [48][32]
    float* a1s = smem + 1968;     // [48][4]
    float* a1d = smem + 2160;
    float* m1  = smem + 2352;
    float* d1  = smem + 2544;
    float* x2  = smem + 2736;     // [48][32]
    float* h2s = smem + 4272;     // [48][9]
    float* a2s = smem + 4704;     // [48]
    float* a2d = smem + 4752;
    float* m2  = smem + 4800;
    float* d2  = smem + 4848;
    float* g2  = smem + 4896;     // [48][9]
    int* srcl  = (int*)(smem + 5328);   // [816]
    int* tgtl  = (int*)(smem + 6144);   // [816]
    int* elist = (int*)(smem + 6960);   // [816]
    int* offs  = (int*)(smem + 7776);   // [49]
    int* cnt   = (int*)(smem + 7825);   // [48]

    for (int i = tid; i < 768; i += 256) { srcl[i] = p.eidx[i]; tgtl[i] = p.eidx[768 + i]; }
    if (tid < 48) { srcl[768 + tid] = tid; tgtl[768 + tid] = tid; }   // self loops
    for (int i = tid; i < 432; i += 256) xin[i] = p.obj[i];
    __syncthreads();

    // CSR over targets, stable edge order (deterministic)
    if (tid < 48) { int c = 0; for (int e = 0; e < 816; ++e) c += (tgtl[e] == tid); cnt[tid] = c; }
    __syncthreads();
    if (tid == 0) { offs[0] = 0; for (int n = 0; n < 48; ++n) offs[n + 1] = offs[n] + cnt[n]; }
    __syncthreads();
    if (tid < 48) { int w = offs[tid]; for (int e = 0; e < 816; ++e) if (tgtl[e] == tid) elist[w++] = e; }

    // h1 = x @ W1 (48x32)
    for (int i = tid; i < 1536; i += 256) {
      int n = i >> 5, j = i & 31;
      float s = 0.f;
      for (int f = 0; f < 9; ++f) s += xin[n * 9 + f] * p.W1[f * 32 + j];
      h1[i] = s;
    }
    __syncthreads();

    for (int i = tid; i < 192; i += 256) {
      int n = i >> 2, h = i & 3;
      float ss = 0.f, sd = 0.f;
      for (int c = 0; c < 8; ++c) {
        float v = h1[n * 32 + h * 8 + c];
        ss += v * p.as1[h * 8 + c];
        sd += v * p.ad1[h * 8 + c];
      }
      a1s[i] = ss; a1d[i] = sd;
    }
    __syncthreads();

    for (int i = tid; i < 192; i += 256) {
      int n = i >> 2, h = i & 3;
      float mx = -1e30f;
      for (int q = offs[n]; q < offs[n + 1]; ++q)
        mx = fmaxf(mx, lrelu(a1s[srcl[elist[q]] * 4 + h] + a1d[i]));
      float sm = 0.f;
      for (int q = offs[n]; q < offs[n + 1]; ++q)
        sm += expf(lrelu(a1s[srcl[elist[q]] * 4 + h] + a1d[i]) - mx);
      m1[i] = mx; d1[i] = sm;
    }
    __syncthreads();

    for (int i = tid; i < 1536; i += 256) {
      int n = i >> 5, j = i & 31, h = j >> 3;
      float acc = 0.f;
      for (int q = offs[n]; q < offs[n + 1]; ++q) {
        int s = srcl[elist[q]];
        acc += expf(lrelu(a1s[s * 4 + h] + a1d[n * 4 + h]) - m1[n * 4 + h]) * h1[s * 32 + j];
      }
      x2[i] = fmaxf(acc / (d1[n * 4 + h] + 1e-16f) + p.b1[j], 0.f);
    }
    __syncthreads();

    for (int i = tid; i < 432; i += 256) {
      int n = i / 9, k = i % 9;
      float s = 0.f;
      for (int c = 0; c < 32; ++c) s += x2[n * 32 + c] * p.W2[c * 9 + k];
      h2s[i] = s;
    }
    __syncthreads();
    if (tid < 48) {
      float ss = 0.f, sd = 0.f;
      for (int k = 0; k < 9; ++k) { ss += h2s[tid * 9 + k] * p.as2[k]; sd += h2s[tid * 9 + k] * p.ad2[k]; }
      a2s[tid] = ss; a2d[tid] = sd;
    }
    __syncthreads();
    if (tid < 48) {
      float mx = -1e30f;
      for (int q = offs[tid]; q < offs[tid + 1]; ++q)
        mx = fmaxf(mx, lrelu(a2s[srcl[elist[q]]] + a2d[tid]));
      float sm = 0.f;
      for (int q = offs[tid]; q < offs[tid + 1]; ++q)
        sm += expf(lrelu(a2s[srcl[elist[q]]] + a2d[tid]) - mx);
      m2[tid] = mx; d2[tid] = sm;
    }
    __syncthreads();
    for (int i = tid; i < 432; i += 256) {
      int n = i / 9, k = i % 9;
      float acc = 0.f;
      for (int q = offs[n]; q < offs[n + 1]; ++q) {
        int s = srcl[elist[q]];
        acc += expf(lrelu(a2s[s] + a2d[n]) - m2[n]) * h2s[s * 9 + k];
      }
      g2[i] = acc / (d2[n] + 1e-16f) + p.b2[k];
    }
    __syncthreads();

    // LayerNorm(9) + residual -> xlg
    if (tid < 48) {
      float mu = 0.f;
      for (int k = 0; k < 9; ++k) mu += g2[tid * 9 + k];
      mu *= (1.f / 9.f);
      float var = 0.f;
      for (int k = 0; k < 9; ++k) { float dd = g2[tid * 9 + k] - mu; var += dd * dd; }
      var *= (1.f / 9.f);
      float is = rsqrtf(var + EPS_LN);
      for (int k = 0; k < 9; ++k)
        p.xlg[tid * 9 + k] = p.lng[k] * (g2[tid * 9 + k] - mu) * is + p.lnb[k] + xin[tid * 9 + k];
    }
  }
  grid.sync();

  // ============== Phase BC: Linear(9->2048)+ReLU, ConvT1 -> hct1 ===========
  for (int job = bid; job < 768; job += 512) {
    const int co = job & 15, n = job >> 4;
    float* xls = smem;          // 9 (padded to 16)
    float* xs  = smem + 16;     // 2048
    float* wsd = smem + 2064;   // 2048
    __syncthreads();            // protect LDS vs previous job's readers
    if (tid < 9) xls[tid] = p.xlg[n * 9 + tid];
    for (int q = tid; q < 2048; q += 256) {
      int ci = q >> 6, t = q & 63;
      wsd[q] = p.ct1W[ci * 1024 + co * 64 + t];
    }
    __syncthreads();
    for (int q = tid; q < 2048; q += 256) {
      float s = p.linb[q];
#pragma unroll
      for (int k = 0; k < 9; ++k) s += xls[k] * p.linW[k * 2048 + q];
      xs[q] = fmaxf(s, 0.f);
    }
    __syncthreads();
    if (tid < 64) {   // conv on wave 0
      const int od = tid >> 3, oh = tid & 7;
      float acc[8];
#pragma unroll
      for (int i = 0; i < 8; ++i) acc[i] = 0.f;
      const int kd0 = 1 - (od & 1), kh0 = 1 - (oh & 1);
#pragma unroll
      for (int kdi = 0; kdi < 2; ++kdi) {
        int kd = kd0 + 2 * kdi;
        int id = (od + 1 - kd) >> 1;
        if ((unsigned)id >= 4u) continue;
#pragma unroll
        for (int khi = 0; khi < 2; ++khi) {
          int kh = kh0 + 2 * khi;
          int ih = (oh + 1 - kh) >> 1;
          if ((unsigned)ih >= 4u) continue;
          for (int ci = 0; ci < 32; ++ci) {
            const float* xr = &xs[ci * 64 + id * 16 + ih * 4];
            const float* wr = &wsd[ci * 64 + kd * 16 + kh * 4];
            float xv[4], wv[4];
#pragma unroll
            for (int t = 0; t < 4; ++t) { xv[t] = xr[t]; wv[t] = wr[t]; }
#pragma unroll
            for (int ow = 0; ow < 8; ++ow) {
              const int kw0 = 1 - (ow & 1);
              const int iw0 = (ow + 1 - kw0) >> 1;
              if (iw0 < 4) acc[ow] += xv[iw0] * wv[kw0];
              if (iw0 - 1 >= 0) acc[ow] += xv[iw0 - 1] * wv[kw0 + 2];
            }
          }
        }
      }
      const float bb = p.ct1b[co];
      float* op = &p.hct1[(n * 16 + co) * 512 + od * 64 + oh * 8];
#pragma unroll
      for (int ow = 0; ow < 8; ++ow) op[ow] = fmaxf(acc[ow] + bb, 0.f);
    }
  }
  grid.sync();

  // ============ Phase D: ConvT2 -> h2 + BN partial sums (bid<432) ==========
  if (bid < 432) {
    const int co = bid % 9, n = bid / 9;
    float* xs  = smem;          // 8192
    float* wsd = smem + 8192;   // 1024
    float* rs  = smem + 9216;   // 256
    float* rq  = smem + 9472;   // 256
    {
      const f4* src = (const f4*)(p.hct1 + (size_t)n * 8192);
      f4* dst = (f4*)xs;
      for (int q = tid; q < 2048; q += 256) dst[q] = src[q];
    }
    for (int q = tid; q < 1024; q += 256) {
      int ci = q >> 6, t = q & 63;
      wsd[q] = p.ct2W[(ci * 9 + co) * 64 + t];
    }
    __syncthreads();

    const int od = tid >> 4, oh = tid & 15;
    float acc[16];
#pragma unroll
    for (int i = 0; i < 16; ++i) acc[i] = 0.f;
    const int kd0 = 1 - (od & 1), kh0 = 1 - (oh & 1);
#pragma unroll
    for (int kdi = 0; kdi < 2; ++kdi) {
      int kd = kd0 + 2 * kdi;
      int id = (od + 1 - kd) >> 1;
      if ((unsigned)id >= 8u) continue;
#pragma unroll
      for (int khi = 0; khi < 2; ++khi) {
        int kh = kh0 + 2 * khi;
        int ih = (oh + 1 - kh) >> 1;
        if ((unsigned)ih >= 8u) continue;
        for (int ci = 0; ci < 16; ++ci) {
          const float* xr = &xs[ci * 512 + id * 64 + ih * 8];
          const float* wr = &wsd[ci * 64 + kd * 16 + kh * 4];
          float xv[8], wv[4];
#pragma unroll
          for (int t = 0; t < 8; ++t) xv[t] = xr[t];
#pragma unroll
          for (int t = 0; t < 4; ++t) wv[t] = wr[t];
#pragma unroll
          for (int ow = 0; ow < 16; ++ow) {
            const int kw0 = 1 - (ow & 1);
            const int iw0 = (ow + 1 - kw0) >> 1;
            if (iw0 < 8) acc[ow] += xv[iw0] * wv[kw0];
            if (iw0 - 1 >= 0) acc[ow] += xv[iw0 - 1] * wv[kw0 + 2];
          }
        }
      }
    }
    const float bb = p.ct2b[co];
    float s = 0.f, q = 0.f;
    f4* op = (f4*)(p.h2 + (size_t)(n * 9 + co) * 4096 + od * 256 + oh * 16);
#pragma unroll
    for (int t = 0; t < 4; ++t) {
      f4 v;
      v.x = acc[4 * t] + bb; v.y = acc[4 * t + 1] + bb;
      v.z = acc[4 * t + 2] + bb; v.w = acc[4 * t + 3] + bb;
      op[t] = v;
      s += v.x + v.y + v.z + v.w;
      q += v.x * v.x + v.y * v.y + v.z * v.z + v.w * v.w;
    }
    rs[tid] = s; rq[tid] = q;
    __syncthreads();
    for (int off = 128; off > 0; off >>= 1) {
      if (tid < off) { rs[tid] += rs[tid + off]; rq[tid] += rq[tid + off]; }
      __syncthreads();
    }
    if (tid == 0) { p.psum[co * 48 + n] = rs[0]; p.pssq[co * 48 + n] = rq[0]; }
  }
  grid.sync();

  // ===== Phase F: BN affine + SEPARABLE trilinear 16->64 + residual add ====
  // Tile = (n,c,slab of 8 od). Pass 1 builds zy-interp plane [8][64][16] in
  // LDS (values bitwise-identical to old per-output a/b/cc); pass 2 does the
  // x-lerp + NT streaming add. 3456 tiles grid-strided over 512 blocks.
  {
    const float sc = p.scp[0];
    const f4* v4 = (const f4*)p.vol;
    f4* o4 = (f4*)p.out;
    float* hs    = smem;          // [4][16][16] z-slices
    float* plane = smem + 1024;   // [8][64][16]
    float* ab    = smem + 9216;   // A, B

    for (int t = bid; t < 3456; t += 512) {
      const int slab = t & 7, c = (t >> 3) % 9, n = t / 72;
      int zb = 2 * slab - 1;
      zb = zb < 0 ? 0 : (zb > 12 ? 12 : zb);
      __syncthreads();   // previous tile's readers done
      {
        const f4* src = (const f4*)(p.h2 + (size_t)(n * 9 + c) * 4096) + zb * 64;
        ((f4*)hs)[tid] = src[tid];   // 4 slices = 256 f4
      }
      if (tid < 64) {   // BN finalize from 48 partials
        float s = (tid < 48) ? p.psum[c * 48 + tid] : 0.f;
        float q = (tid < 48) ? p.pssq[c * 48 + tid] : 0.f;
#pragma unroll
        for (int off = 32; off > 0; off >>= 1) {
          s += __shfl_down(s, off);
          q += __shfl_down(q, off);
        }
        if (tid == 0) {
          float mean = s * (1.f / 196608.f);
          float var = q * (1.f / 196608.f) - mean * mean;
          float Aa = p.bng[c] * rsqrtf(var + EPS_BN);
          ab[0] = Aa;
          ab[1] = p.bnb[c] - Aa * mean;
        }
      }
      __syncthreads();

      const int od_base = slab * 8;
      // pass 1: zy plane
#pragma unroll
      for (int j = 0; j < 32; ++j) {
        int e = tid + j * 256;
        int x = e & 15, oh = (e >> 4) & 63, od = e >> 10;
        int z0, z1, y0, y1; float fz, fy;
        axis16(od_base + od, z0, z1, fz);
        axis16(oh, y0, y1, fy);
        float w00 = (1.f - fz) * (1.f - fy), w01 = (1.f - fz) * fy;
        float w10 = fz * (1.f - fy), w11 = fz * fy;
        int bz0 = (z0 - zb) << 8, bz1 = (z1 - zb) << 8;
        int by0 = y0 << 4, by1 = y1 << 4;
        plane[e] = w00 * hs[bz0 + by0 + x] + w01 * hs[bz0 + by1 + x]
                 + w10 * hs[bz1 + by0 + x] + w11 * hs[bz1 + by1 + x];
      }
      __syncthreads();

      const float Aa = ab[0], Bb = ab[1];
      const size_t gbase = ((size_t)(n * 9 + c) * 64 + od_base) * 1024;  // f4 units
      // pass 2: x-lerp + stream
#pragma unroll 4
      for (int it = 0; it < 32; ++it) {
        int u = tid + it * 256;
        int owq = u & 15, base = (u >> 4) << 4;   // odl*1024 + oh*16
        int xa = owq - 1 < 0 ? 0 : owq - 1;
        int xc = owq + 1 > 15 ? 15 : owq + 1;
        float A = plane[base + xa], B = plane[base + owq], C = plane[base + xc];
        float p0 = A + 0.625f * (B - A);
        float p1 = A + 0.875f * (B - A);
        float p2 = B + 0.125f * (C - B);
        float p3 = B + 0.375f * (C - B);
        size_t g = gbase + (size_t)u;
        f4 vv = __builtin_nontemporal_load(&v4[g]);
        f4 oo;
        oo.x = vv.x + sc * fmaf(Aa, p0, Bb);
        oo.y = vv.y + sc * fmaf(Aa, p1, Bb);
        oo.z = vv.z + sc * fmaf(Aa, p2, Bb);
        oo.w = vv.w + sc * fmaf(Aa, p3, Bb);
        __builtin_nontemporal_store(oo, &o4[g]);
      }
    }
  }
}

// ===========================================================================
// Fallback (non-cooperative) pipeline — identical math, R6 kernels.
// ===========================================================================
__global__ __launch_bounds__(512) void kA(
    const float* __restrict__ obj, const int* __restrict__ eidx,
    const float* __restrict__ W1, const float* __restrict__ as1w,
    const float* __restrict__ ad1w, const float* __restrict__ b1,
    const float* __restrict__ W2, const float* __restrict__ as2w,
    const float* __restrict__ ad2w, const float* __restrict__ b2,
    const float* __restrict__ lng, const float* __restrict__ lnb,
    float* __restrict__ xlg)
{
  const int tid = threadIdx.x;
  __shared__ float xin[48][9];
  __shared__ float h1[48][32];
  __shared__ float a1s[48][4], a1d[48][4];
  __shared__ float m1[48][4], d1[48][4];
  __shared__ float x2[48][32];
  __shared__ float h2s[48][9];
  __shared__ float a2s[48], a2d[48], m2[48], d2[48];
  __shared__ float g2[48][9];
  __shared__ int srcl[816], tgtl[816], elist[816];
  __shared__ int offs[49], cnt[48];

  for (int i = tid; i < 768; i += 512) { srcl[i] = eidx[i]; tgtl[i] = eidx[768 + i]; }
  if (tid < 48) { srcl[768 + tid] = tid; tgtl[768 + tid] = tid; }
  for (int i = tid; i < 432; i += 512) xin[i / 9][i % 9] = obj[i];
  __syncthreads();
  if (tid < 48) { int c = 0; for (int e = 0; e < 816; ++e) c += (tgtl[e] == tid); cnt[tid] = c; }
  __syncthreads();
  if (tid == 0) { offs[0] = 0; for (int n = 0; n < 48; ++n) offs[n + 1] = offs[n] + cnt[n]; }
  __syncthreads();
  if (tid < 48) { int p = offs[tid]; for (int e = 0; e < 816; ++e) if (tgtl[e] == tid) elist[p++] = e; }
  for (int i = tid; i < 1536; i += 512) {
    int n = i >> 5, j = i & 31;
    float s = 0.f;
    for (int f = 0; f < 9; ++f) s += xin[n][f] * W1[f * 32 + j];
    h1[n][j] = s;
  }
  __syncthreads();
  for (int i = tid; i < 192; i += 512) {
    int n = i >> 2, h = i & 3;
    float ss = 0.f, sd = 0.f;
    for (int c = 0; c < 8; ++c) {
      float v = h1[n][h * 8 + c];
      ss += v * as1w[h * 8 + c];
      sd += v * ad1w[h * 8 + c];
    }
    a1s[n][h] = ss; a1d[n][h] = sd;
  }
  __syncthreads();
  for (int i = tid; i < 192; i += 512) {
    int n = i >> 2, h = i & 3;
    float mx = -1e30f;
    for (int p = offs[n]; p < offs[n + 1]; ++p)
      mx = fmaxf(mx, lrelu(a1s[srcl[elist[p]]][h] + a1d[n][h]));
    float sm = 0.f;
    for (int p = offs[n]; p < offs[n + 1]; ++p)
      sm += expf(lrelu(a1s[srcl[elist[p]]][h] + a1d[n][h]) - mx);
    m1[n][h] = mx; d1[n][h] = sm;
  }
  __syncthreads();
  for (int i = tid; i < 1536; i += 512) {
    int n = i >> 5, j = i & 31, h = j >> 3;
    float acc = 0.f;
    for (int p = offs[n]; p < offs[n + 1]; ++p) {
      int s = srcl[elist[p]];
      acc += expf(lrelu(a1s[s][h] + a1d[n][h]) - m1[n][h]) * h1[s][j];
    }
    x2[n][j] = fmaxf(acc / (d1[n][h] + 1e-16f) + b1[j], 0.f);
  }
  __syncthreads();
  for (int i = tid; i < 432; i += 512) {
    int n = i / 9, k = i % 9;
    float s = 0.f;
    for (int c = 0; c < 32; ++c) s += x2[n][c] * W2[c * 9 + k];
    h2s[n][k] = s;
  }
  __syncthreads();
  if (tid < 48) {
    float ss = 0.f, sd = 0.f;
    for (int k = 0; k < 9; ++k) { ss += h2s[tid][k] * as2w[k]; sd += h2s[tid][k] * ad2w[k]; }
    a2s[tid] = ss; a2d[tid] = sd;
  }
  __syncthreads();
  if (tid < 48) {
    int n = tid;
    float mx = -1e30f;
    for (int p = offs[n]; p < offs[n + 1]; ++p)
      mx = fmaxf(mx, lrelu(a2s[srcl[elist[p]]] + a2d[n]));
    float sm = 0.f;
    for (int p = offs[n]; p < offs[n + 1]; ++p)
      sm += expf(lrelu(a2s[srcl[elist[p]]] + a2d[n]) - mx);
    m2[n] = mx; d2[n] = sm;
  }
  __syncthreads();
  for (int i = tid; i < 432; i += 512) {
    int n = i / 9, k = i % 9;
    float acc = 0.f;
    for (int p = offs[n]; p < offs[n + 1]; ++p) {
      int s = srcl[elist[p]];
      acc += expf(lrelu(a2s[s] + a2d[n]) - m2[n]) * h2s[s][k];
    }
    g2[n][k] = acc / (d2[n] + 1e-16f) + b2[k];
  }
  __syncthreads();
  if (tid < 48) {
    float mu = 0.f;
    for (int k = 0; k < 9; ++k) mu += g2[tid][k];
    mu *= (1.f / 9.f);
    float var = 0.f;
    for (int k = 0; k < 9; ++k) { float dd = g2[tid][k] - mu; var += dd * dd; }
    var *= (1.f / 9.f);
    float is = rsqrtf(var + EPS_LN);
    for (int k = 0; k < 9; ++k)
      xlg[tid * 9 + k] = lng[k] * (g2[tid][k] - mu) * is + lnb[k] + xin[tid][k];
  }
}

__global__ __launch_bounds__(256) void kBC(
    const float* __restrict__ xlg, const float* __restrict__ linW,
    const float* __restrict__ linb, const float* __restrict__ w,
    const float* __restrict__ bias, float* __restrict__ outp)
{
  const int co = blockIdx.x, n = blockIdx.y, tid = threadIdx.x;
  __shared__ float xls[9];
  __shared__ float xs[2048];
  __shared__ float wsd[2048];
  if (tid < 9) xls[tid] = xlg[n * 9 + tid];
  for (int q = tid; q < 2048; q += 256) {
    int ci = q >> 6, t = q & 63;
    wsd[q] = w[ci * 1024 + co * 64 + t];
  }
  __syncthreads();
  for (int q = tid; q < 2048; q += 256) {
    float s = linb[q];
#pragma unroll
    for (int k = 0; k < 9; ++k) s += xls[k] * linW[k * 2048 + q];
    xs[q] = fmaxf(s, 0.f);
  }
  __syncthreads();
  if (tid >= 64) return;
  const int od = tid >> 3, oh = tid & 7;
  float acc[8];
#pragma unroll
  for (int i = 0; i < 8; ++i) acc[i] = 0.f;
  const int kd0 = 1 - (od & 1), kh0 = 1 - (oh & 1);
#pragma unroll
  for (int kdi = 0; kdi < 2; ++kdi) {
    int kd = kd0 + 2 * kdi;
    int id = (od + 1 - kd) >> 1;
    if ((unsigned)id >= 4u) continue;
#pragma unroll
    for (int khi = 0; khi < 2; ++khi) {
      int kh = kh0 + 2 * khi;
      int ih = (oh + 1 - kh) >> 1;
      if ((unsigned)ih >= 4u) continue;
      for (int ci = 0; ci < 32; ++ci) {
        const float* xr = &xs[ci * 64 + id * 16 + ih * 4];
        const float* wr = &wsd[ci * 64 + kd * 16 + kh * 4];
        float xv[4], wv[4];
#pragma unroll
        for (int t = 0; t < 4; ++t) { xv[t] = xr[t]; wv[t] = wr[t]; }
#pragma unroll
        for (int ow = 0; ow < 8; ++ow) {
          const int kw0 = 1 - (ow & 1);
          const int iw0 = (ow + 1 - kw0) >> 1;
          if (iw0 < 4) acc[ow] += xv[iw0] * wv[kw0];
          if (iw0 - 1 >= 0) acc[ow] += xv[iw0 - 1] * wv[kw0 + 2];
        }
      }
    }
  }
  const float bb = bias[co];
  float* op = &outp[(n * 16 + co) * 512 + od * 64 + oh * 8];
#pragma unroll
  for (int ow = 0; ow < 8; ++ow) op[ow] = fmaxf(acc[ow] + bb, 0.f);
}

__global__ __launch_bounds__(256) void kD(
    const float* __restrict__ x, const float* __restrict__ w,
    const float* __restrict__ bias, float* __restrict__ outp,
    float* __restrict__ psum, float* __restrict__ pssq)
{
  const int co = blockIdx.x, n = blockIdx.y, tid = threadIdx.x;
  __shared__ float xs[8192];
  __shared__ float wsd[1024];
  __shared__ float rs[256], rq[256];
  {
    const float4* src = (const float4*)(x + (size_t)n * 8192);
    float4* dst = (float4*)xs;
    for (int q = tid; q < 2048; q += 256) dst[q] = src[q];
  }
  for (int q = tid; q < 1024; q += 256) {
    int ci = q >> 6, t = q & 63;
    wsd[q] = w[(ci * 9 + co) * 64 + t];
  }
  __syncthreads();
  const int od = tid >> 4, oh = tid & 15;
  float acc[16];
#pragma unroll
  for (int i = 0; i < 16; ++i) acc[i] = 0.f;
  const int kd0 = 1 - (od & 1), kh0 = 1 - (oh & 1);
#pragma unroll
  for (int kdi = 0; kdi < 2; ++kdi) {
    int kd = kd0 + 2 * kdi;
    int id = (od + 1 - kd) >> 1;
    if ((unsigned)id >= 8u) continue;
#pragma unroll
    for (int khi = 0; khi < 2; ++khi) {
      int kh = kh0 + 2 * khi;
      int ih = (oh + 1 - kh) >> 1;
      if ((unsigned)ih >= 8u) continue;
      for (int ci = 0; ci < 16; ++ci) {
        const float* xr = &xs[ci * 512 + id * 64 + ih * 8];
        const float* wr = &wsd[ci * 64 + kd * 16 + kh * 4];
        float xv[8], wv[4];
#pragma unroll
        for (int t = 0; t < 8; ++t) xv[t] = xr[t];
#pragma unroll
        for (int t = 0; t < 4; ++t) wv[t] = wr[t];
#pragma unroll
        for (int ow = 0; ow < 16; ++ow) {
          const int kw0 = 1 - (ow & 1);
          const int iw0 = (ow + 1 - kw0) >> 1;
          if (iw0 < 8) acc[ow] += xv[iw0] * wv[kw0];
          if (iw0 - 1 >= 0) acc[ow] += xv[iw0 - 1] * wv[kw0 + 2];
        }
      }
    }
  }
  const float bb = bias[co];
  float s = 0.f, q = 0.f;
  float4* op = (float4*)(outp + (size_t)(n * 9 + co) * 4096 + od * 256 + oh * 16);
#pragma unroll
  for (int t = 0; t < 4; ++t) {
    float4 v;
    v.x = acc[4 * t] + bb; v.y = acc[4 * t + 1] + bb;
    v.z = acc[4 * t + 2] + bb; v.w = acc[4 * t + 3] + bb;
    op[t] = v;
    s += v.x + v.y + v.z + v.w;
    q += v.x * v.x + v.y * v.y + v.z * v.z + v.w * v.w;
  }
  rs[tid] = s; rq[tid] = q;
  __syncthreads();
  for (int off = 128; off > 0; off >>= 1) {
    if (tid < off) { rs[tid] += rs[tid + off]; rq[tid] += rq[tid + off]; }
    __syncthreads();
  }
  if (tid == 0) { psum[co * 48 + n] = rs[0]; pssq[co * 48 + n] = rq[0]; }
}

__global__ __launch_bounds__(256) void kF(
    const float* __restrict__ vol, const float* __restrict__ h2,
    const float* __restrict__ psum, const float* __restrict__ pssq,
    const float* __restrict__ bng, const float* __restrict__ bnb,
    const float* __restrict__ scp, float* __restrict__ outp)
{
  const int slab = blockIdx.x, c = blockIdx.y, n = blockIdx.z, tid = threadIdx.x;
  __shared__ float hs[1024];
  __shared__ float abS[2];
  int zb = 2 * slab - 1;
  zb = zb < 0 ? 0 : (zb > 12 ? 12 : zb);
  {
    const float4* src = (const float4*)(h2 + (size_t)(n * 9 + c) * 4096) + zb * 64;
    ((float4*)hs)[tid] = src[tid];
  }
  if (tid < 64) {
    float s = (tid < 48) ? psum[c * 48 + tid] : 0.f;
    float q = (tid < 48) ? pssq[c * 48 + tid] : 0.f;
#pragma unroll
    for (int off = 32; off > 0; off >>= 1) {
      s += __shfl_down(s, off);
      q += __shfl_down(q, off);
    }
    if (tid == 0) {
      float mean = s * (1.f / 196608.f);
      float var = q * (1.f / 196608.f) - mean * mean;
      float Aa = bng[c] * rsqrtf(var + EPS_BN);
      abS[0] = Aa;
      abS[1] = bnb[c] - Aa * mean;
    }
  }
  const float sc = scp[0];
  __syncthreads();
  const float Aa = abS[0], Bb = abS[1];
  const int od_base = slab * 8;
  const size_t gbase = ((size_t)(n * 9 + c) * 64 + od_base) * 1024;
  const f4* v4 = (const f4*)vol;
  f4* o4 = (f4*)outp;
  for (int it = 0; it < 32; ++it) {
    int u = tid + it * 256;
    int owq = u & 15, oh = (u >> 4) & 63, odl = u >> 10;
    int z0, z1, y0, y1; float fz, fy;
    axis16(od_base + odl, z0, z1, fz);
    axis16(oh, y0, y1, fy);
    float w00 = (1.f - fz) * (1.f - fy), w01 = (1.f - fz) * fy;
    float w10 = fz * (1.f - fy), w11 = fz * fy;
    int bz0 = (z0 - zb) << 8, bz1 = (z1 - zb) << 8;
    int by0 = y0 << 4, by1 = y1 << 4;
    int xa = owq - 1 < 0 ? 0 : owq - 1;
    int xc = owq + 1 > 15 ? 15 : owq + 1;
    float a = w00 * hs[bz0 + by0 + xa] + w01 * hs[bz0 + by1 + xa]
            + w10 * hs[bz1 + by0 + xa] + w11 * hs[bz1 + by1 + xa];
    float b = w00 * hs[bz0 + by0 + owq] + w01 * hs[bz0 + by1 + owq]
            + w10 * hs[bz1 + by0 + owq] + w11 * hs[bz1 + by1 + owq];
    float cc = w00 * hs[bz0 + by0 + xc] + w01 * hs[bz0 + by1 + xc]
             + w10 * hs[bz1 + by0 + xc] + w11 * hs[bz1 + by1 + xc];
    float p0 = a + 0.625f * (b - a);
    float p1 = a + 0.875f * (b - a);
    float p2 = b + 0.125f * (cc - b);
    float p3 = b + 0.375f * (cc - b);
    size_t g = gbase + (size_t)u;
    f4 vv = __builtin_nontemporal_load(&v4[g]);
    f4 oo;
    oo.x = vv.x + sc * fmaf(Aa, p0, Bb);
    oo.y = vv.y + sc * fmaf(Aa, p1, Bb);
    oo.z = vv.z + sc * fmaf(Aa, p2, Bb);
    oo.w = vv.w + sc * fmaf(Aa, p3, Bb);
    __builtin_nontemporal_store(oo, &o4[g]);
  }
}

// ---------------------------------------------------------------------------
extern "C" void kernel_launch(void* const* d_in, const int* in_sizes, int n_in,
                              void* d_out, int out_size, void* d_ws, size_t ws_size,
                              hipStream_t stream) {
  (void)in_sizes; (void)n_in; (void)out_size; (void)ws_size;
  float* ws = (float*)d_ws;
  P p;
  p.obj  = (const float*)d_in[0];
  p.eidx = (const int*)d_in[1];
  p.vol  = (const float*)d_in[2];
  p.W1   = (const float*)d_in[3];
  p.as1  = (const float*)d_in[4];
  p.ad1  = (const float*)d_in[5];
  p.b1   = (const float*)d_in[6];
  p.W2   = (const float*)d_in[7];
  p.as2  = (const float*)d_in[8];
  p.ad2  = (const float*)d_in[9];
  p.b2   = (const float*)d_in[10];
  p.lng  = (const float*)d_in[11];
  p.lnb  = (const float*)d_in[12];
  p.scp  = (const float*)d_in[13];
  p.linW = (const float*)d_in[14];
  p.linb = (const float*)d_in[15];
  p.ct1W = (const float*)d_in[16];
  p.ct1b = (const float*)d_in[17];
  p.ct2W = (const float*)d_in[18];
  p.ct2b = (const float*)d_in[19];
  p.bng  = (const float*)d_in[20];
  p.bnb  = (const float*)d_in[21];
  p.out  = (float*)d_out;
  p.xlg  = ws;                 // 432 f
  p.hct1 = ws + 432;           // 393216 f
  p.h2   = ws + 393648;        // 1769472 f
  p.psum = ws + 2163120;       // 432 f
  p.pssq = ws + 2163552;       // 432 f  (~8.66 MB)

  void* args[] = { (void*)&p };
  hipError_t err = hipLaunchCooperativeKernel((const void*)mega, dim3(512), dim3(256),
                                              args, 0, stream);
  if (err != hipSuccess) {
    // Fallback: non-cooperative 4-kernel pipeline (identical math).
    kA<<<1, 512, 0, stream>>>(p.obj, p.eidx, p.W1, p.as1, p.ad1, p.b1, p.W2,
                              p.as2, p.ad2, p.b2, p.lng, p.lnb, p.xlg);
    kBC<<<dim3(16, 48), 256, 0, stream>>>(p.xlg, p.linW, p.linb, p.ct1W, p.ct1b, p.hct1);
    kD<<<dim3(9, 48), 256, 0, stream>>>(p.hct1, p.ct2W, p.ct2b, p.h2, p.psum, p.pssq);
    kF<<<dim3(8, 9, 48), 256, 0, stream>>>(p.vol, p.h2, p.psum, p.pssq, p.bng,
                                           p.bnb, p.scp, p.out);
  }
}

// Round 8
// 294.867 us; speedup vs baseline: 2.4624x; 2.4624x over previous
//
#include <hip/hip_runtime.h>

#define EPS_LN 1e-5f
#define EPS_BN 1e-5f

typedef float f4 __attribute__((ext_vector_type(4)));

__device__ __forceinline__ float lrelu(float v) { return v >= 0.f ? v : 0.2f * v; }

// half-pixel 16->64 axis map: src = 0.25*o - 0.375 = (2o-3)/8
__device__ __forceinline__ void axis16(int o, int& i0, int& i1, float& f) {
  int t = 2 * o - 3;
  int q = (t >= 0) ? (t >> 3) : -1;       // floor(t/8); t >= -3 so floor=-1
  f = (float)(t - 8 * q) * 0.125f;
  i0 = q < 0 ? 0 : q;
  i1 = q + 1 > 15 ? 15 : q + 1;
}

// ---------------------------------------------------------------------------
// Kernel A: GAT1 (+ReLU) -> GAT2 -> LayerNorm + residual -> xl (48x9) to ws
// Single block; N=48, E=768+48 self loops = 816. Everything lives in LDS.
// (unchanged from R6)
// ---------------------------------------------------------------------------
__global__ __launch_bounds__(512) void kA(
    const float* __restrict__ obj, const int* __restrict__ eidx,
    const float* __restrict__ W1, const float* __restrict__ as1w,
    const float* __restrict__ ad1w, const float* __restrict__ b1,
    const float* __restrict__ W2, const float* __restrict__ as2w,
    const float* __restrict__ ad2w, const float* __restrict__ b2,
    const float* __restrict__ lng, const float* __restrict__ lnb,
    float* __restrict__ xlg)
{
  const int tid = threadIdx.x;
  __shared__ float xin[48][9];
  __shared__ float h1[48][32];
  __shared__ float a1s[48][4], a1d[48][4];
  __shared__ float m1[48][4], d1[48][4];
  __shared__ float x2[48][32];
  __shared__ float h2s[48][9];
  __shared__ float a2s[48], a2d[48], m2[48], d2[48];
  __shared__ float g2[48][9];
  __shared__ int srcl[816], tgtl[816], elist[816];
  __shared__ int offs[49], cnt[48];

  for (int i = tid; i < 768; i += 512) { srcl[i] = eidx[i]; tgtl[i] = eidx[768 + i]; }
  if (tid < 48) { srcl[768 + tid] = tid; tgtl[768 + tid] = tid; }   // self loops
  for (int i = tid; i < 432; i += 512) xin[i / 9][i % 9] = obj[i];
  __syncthreads();
  if (tid < 48) { int c = 0; for (int e = 0; e < 816; ++e) c += (tgtl[e] == tid); cnt[tid] = c; }
  __syncthreads();
  if (tid == 0) { offs[0] = 0; for (int n = 0; n < 48; ++n) offs[n + 1] = offs[n] + cnt[n]; }
  __syncthreads();
  if (tid < 48) { int p = offs[tid]; for (int e = 0; e < 816; ++e) if (tgtl[e] == tid) elist[p++] = e; }
  for (int i = tid; i < 1536; i += 512) {
    int n = i >> 5, j = i & 31;
    float s = 0.f;
    for (int f = 0; f < 9; ++f) s += xin[n][f] * W1[f * 32 + j];
    h1[n][j] = s;
  }
  __syncthreads();
  for (int i = tid; i < 192; i += 512) {
    int n = i >> 2, h = i & 3;
    float ss = 0.f, sd = 0.f;
    for (int c = 0; c < 8; ++c) {
      float v = h1[n][h * 8 + c];
      ss += v * as1w[h * 8 + c];
      sd += v * ad1w[h * 8 + c];
    }
    a1s[n][h] = ss; a1d[n][h] = sd;
  }
  __syncthreads();
  for (int i = tid; i < 192; i += 512) {
    int n = i >> 2, h = i & 3;
    float mx = -1e30f;
    for (int p = offs[n]; p < offs[n + 1]; ++p)
      mx = fmaxf(mx, lrelu(a1s[srcl[elist[p]]][h] + a1d[n][h]));
    float sm = 0.f;
    for (int p = offs[n]; p < offs[n + 1]; ++p)
      sm += expf(lrelu(a1s[srcl[elist[p]]][h] + a1d[n][h]) - mx);
    m1[n][h] = mx; d1[n][h] = sm;
  }
  __syncthreads();
  for (int i = tid; i < 1536; i += 512) {
    int n = i >> 5, j = i & 31, h = j >> 3;
    float acc = 0.f;
    for (int p = offs[n]; p < offs[n + 1]; ++p) {
      int s = srcl[elist[p]];
      acc += expf(lrelu(a1s[s][h] + a1d[n][h]) - m1[n][h]) * h1[s][j];
    }
    x2[n][j] = fmaxf(acc / (d1[n][h] + 1e-16f) + b1[j], 0.f);
  }
  __syncthreads();
  for (int i = tid; i < 432; i += 512) {
    int n = i / 9, k = i % 9;
    float s = 0.f;
    for (int c = 0; c < 32; ++c) s += x2[n][c] * W2[c * 9 + k];
    h2s[n][k] = s;
  }
  __syncthreads();
  if (tid < 48) {
    float ss = 0.f, sd = 0.f;
    for (int k = 0; k < 9; ++k) { ss += h2s[tid][k] * as2w[k]; sd += h2s[tid][k] * ad2w[k]; }
    a2s[tid] = ss; a2d[tid] = sd;
  }
  __syncthreads();
  if (tid < 48) {
    int n = tid;
    float mx = -1e30f;
    for (int p = offs[n]; p < offs[n + 1]; ++p)
      mx = fmaxf(mx, lrelu(a2s[srcl[elist[p]]] + a2d[n]));
    float sm = 0.f;
    for (int p = offs[n]; p < offs[n + 1]; ++p)
      sm += expf(lrelu(a2s[srcl[elist[p]]] + a2d[n]) - mx);
    m2[n] = mx; d2[n] = sm;
  }
  __syncthreads();
  for (int i = tid; i < 432; i += 512) {
    int n = i / 9, k = i % 9;
    float acc = 0.f;
    for (int p = offs[n]; p < offs[n + 1]; ++p) {
      int s = srcl[elist[p]];
      acc += expf(lrelu(a2s[s] + a2d[n]) - m2[n]) * h2s[s][k];
    }
    g2[n][k] = acc / (d2[n] + 1e-16f) + b2[k];
  }
  __syncthreads();
  if (tid < 48) {
    float mu = 0.f;
    for (int k = 0; k < 9; ++k) mu += g2[tid][k];
    mu *= (1.f / 9.f);
    float var = 0.f;
    for (int k = 0; k < 9; ++k) { float dd = g2[tid][k] - mu; var += dd * dd; }
    var *= (1.f / 9.f);
    float is = rsqrtf(var + EPS_LN);
    for (int k = 0; k < 9; ++k)
      xlg[tid * 9 + k] = lng[k] * (g2[tid][k] - mu) * is + lnb[k] + xin[tid][k];
  }
}

// ---------------------------------------------------------------------------
// Kernel BC: Linear(9->2048)+ReLU per block into LDS, then ConvT1 -> hct1.
// (unchanged from R6)
// ---------------------------------------------------------------------------
__global__ __launch_bounds__(256) void kBC(
    const float* __restrict__ xlg, const float* __restrict__ linW,
    const float* __restrict__ linb, const float* __restrict__ w,
    const float* __restrict__ bias, float* __restrict__ outp)
{
  const int co = blockIdx.x, n = blockIdx.y, tid = threadIdx.x;
  __shared__ float xls[9];
  __shared__ float xs[2048];
  __shared__ float wsd[2048];
  if (tid < 9) xls[tid] = xlg[n * 9 + tid];
  for (int q = tid; q < 2048; q += 256) {
    int ci = q >> 6, t = q & 63;
    wsd[q] = w[ci * 1024 + co * 64 + t];
  }
  __syncthreads();
  for (int q = tid; q < 2048; q += 256) {
    float s = linb[q];
#pragma unroll
    for (int k = 0; k < 9; ++k) s += xls[k] * linW[k * 2048 + q];
    xs[q] = fmaxf(s, 0.f);
  }
  __syncthreads();
  if (tid >= 64) return;
  const int od = tid >> 3, oh = tid & 7;
  float acc[8];
#pragma unroll
  for (int i = 0; i < 8; ++i) acc[i] = 0.f;
  const int kd0 = 1 - (od & 1), kh0 = 1 - (oh & 1);
#pragma unroll
  for (int kdi = 0; kdi < 2; ++kdi) {
    int kd = kd0 + 2 * kdi;
    int id = (od + 1 - kd) >> 1;
    if ((unsigned)id >= 4u) continue;
#pragma unroll
    for (int khi = 0; khi < 2; ++khi) {
      int kh = kh0 + 2 * khi;
      int ih = (oh + 1 - kh) >> 1;
      if ((unsigned)ih >= 4u) continue;
      for (int ci = 0; ci < 32; ++ci) {
        const float* xr = &xs[ci * 64 + id * 16 + ih * 4];
        const float* wr = &wsd[ci * 64 + kd * 16 + kh * 4];
        float xv[4], wv[4];
#pragma unroll
        for (int t = 0; t < 4; ++t) { xv[t] = xr[t]; wv[t] = wr[t]; }
#pragma unroll
        for (int ow = 0; ow < 8; ++ow) {
          const int kw0 = 1 - (ow & 1);
          const int iw0 = (ow + 1 - kw0) >> 1;
          if (iw0 < 4) acc[ow] += xv[iw0] * wv[kw0];
          if (iw0 - 1 >= 0) acc[ow] += xv[iw0 - 1] * wv[kw0 + 2];
        }
      }
    }
  }
  const float bb = bias[co];
  float* op = &outp[(n * 16 + co) * 512 + od * 64 + oh * 8];
#pragma unroll
  for (int ow = 0; ow < 8; ++ow) op[ow] = fmaxf(acc[ow] + bb, 0.f);
}

// ---------------------------------------------------------------------------
// Kernel D: ConvT2 -> h2 (48,9,16^3) + BN partial sums. (unchanged from R6)
// ---------------------------------------------------------------------------
__global__ __launch_bounds__(256) void kD(
    const float* __restrict__ x, const float* __restrict__ w,
    const float* __restrict__ bias, float* __restrict__ outp,
    float* __restrict__ psum, float* __restrict__ pssq)
{
  const int co = blockIdx.x, n = blockIdx.y, tid = threadIdx.x;
  __shared__ float xs[8192];
  __shared__ float wsd[1024];
  __shared__ float rs[256], rq[256];
  {
    const float4* src = (const float4*)(x + (size_t)n * 8192);
    float4* dst = (float4*)xs;
    for (int q = tid; q < 2048; q += 256) dst[q] = src[q];
  }
  for (int q = tid; q < 1024; q += 256) {
    int ci = q >> 6, t = q & 63;
    wsd[q] = w[(ci * 9 + co) * 64 + t];
  }
  __syncthreads();
  const int od = tid >> 4, oh = tid & 15;
  float acc[16];
#pragma unroll
  for (int i = 0; i < 16; ++i) acc[i] = 0.f;
  const int kd0 = 1 - (od & 1), kh0 = 1 - (oh & 1);
#pragma unroll
  for (int kdi = 0; kdi < 2; ++kdi) {
    int kd = kd0 + 2 * kdi;
    int id = (od + 1 - kd) >> 1;
    if ((unsigned)id >= 8u) continue;
#pragma unroll
    for (int khi = 0; khi < 2; ++khi) {
      int kh = kh0 + 2 * khi;
      int ih = (oh + 1 - kh) >> 1;
      if ((unsigned)ih >= 8u) continue;
      for (int ci = 0; ci < 16; ++ci) {
        const float* xr = &xs[ci * 512 + id * 64 + ih * 8];
        const float* wr = &wsd[ci * 64 + kd * 16 + kh * 4];
        float xv[8], wv[4];
#pragma unroll
        for (int t = 0; t < 8; ++t) xv[t] = xr[t];
#pragma unroll
        for (int t = 0; t < 4; ++t) wv[t] = wr[t];
#pragma unroll
        for (int ow = 0; ow < 16; ++ow) {
          const int kw0 = 1 - (ow & 1);
          const int iw0 = (ow + 1 - kw0) >> 1;
          if (iw0 < 8) acc[ow] += xv[iw0] * wv[kw0];
          if (iw0 - 1 >= 0) acc[ow] += xv[iw0 - 1] * wv[kw0 + 2];
        }
      }
    }
  }
  const float bb = bias[co];
  float s = 0.f, q = 0.f;
  float4* op = (float4*)(outp + (size_t)(n * 9 + co) * 4096 + od * 256 + oh * 16);
#pragma unroll
  for (int t = 0; t < 4; ++t) {
    float4 v;
    v.x = acc[4 * t] + bb; v.y = acc[4 * t + 1] + bb;
    v.z = acc[4 * t + 2] + bb; v.w = acc[4 * t + 3] + bb;
    op[t] = v;
    s += v.x + v.y + v.z + v.w;
    q += v.x * v.x + v.y * v.y + v.z * v.z + v.w * v.w;
  }
  rs[tid] = s; rq[tid] = q;
  __syncthreads();
  for (int off = 128; off > 0; off >>= 1) {
    if (tid < off) { rs[tid] += rs[tid + off]; rq[tid] += rq[tid + off]; }
    __syncthreads();
  }
  if (tid == 0) { psum[co * 48 + n] = rs[0]; pssq[co * 48 + n] = rq[0]; }
}

// ---------------------------------------------------------------------------
// Kernel F2: out = volumes + scale * (A_c * trilinear16->64(h2) + B_c)
// NEW: separable zy-plane in LDS (values bitwise-identical to the verified
// mega phase-F), then an x-lerp streaming pass with EXPLICIT MLP-8:
// per batch, 8 independent plain global loads are issued before any use,
// hiding HBM latency (~900ns) under the LDS interp work. 512 thr/block,
// 3456 blocks, ~37 KB LDS (2 blocks/CU, 16 waves/CU).
// ---------------------------------------------------------------------------
__global__ __launch_bounds__(512) void kF2(
    const float* __restrict__ vol, const float* __restrict__ h2,
    const float* __restrict__ psum, const float* __restrict__ pssq,
    const float* __restrict__ bng, const float* __restrict__ bnb,
    const float* __restrict__ scp, float* __restrict__ outp)
{
  const int slab = blockIdx.x, c = blockIdx.y, n = blockIdx.z, tid = threadIdx.x;
  __shared__ float hs[1024];     // 4 z-slices of h2[n][c] : [4][16][16]
  __shared__ float plane[8192];  // zy-interp plane [8][64][16]
  __shared__ float abS[2];
  int zb = 2 * slab - 1;
  zb = zb < 0 ? 0 : (zb > 12 ? 12 : zb);
  if (tid < 256) {
    const f4* src = (const f4*)(h2 + (size_t)(n * 9 + c) * 4096) + zb * 64;
    ((f4*)hs)[tid] = src[tid];   // 256 f4 = 4 slices
  }
  if (tid < 64) {   // BN finalize: reduce 48 partials in wave 0
    float s = (tid < 48) ? psum[c * 48 + tid] : 0.f;
    float q = (tid < 48) ? pssq[c * 48 + tid] : 0.f;
#pragma unroll
    for (int off = 32; off > 0; off >>= 1) {
      s += __shfl_down(s, off);
      q += __shfl_down(q, off);
    }
    if (tid == 0) {
      float mean = s * (1.f / 196608.f);
      float var = q * (1.f / 196608.f) - mean * mean;
      float Aa = bng[c] * rsqrtf(var + EPS_BN);
      abS[0] = Aa;
      abS[1] = bnb[c] - Aa * mean;
    }
  }
  const float sc = scp[0];
  __syncthreads();

  const int od_base = slab * 8;
  // pass 1: zy plane (bitwise-identical to verified per-output a/b/cc)
#pragma unroll
  for (int j = 0; j < 16; ++j) {
    int e = tid + j * 512;
    int x = e & 15, oh = (e >> 4) & 63, od = e >> 10;
    int z0, z1, y0, y1; float fz, fy;
    axis16(od_base + od, z0, z1, fz);
    axis16(oh, y0, y1, fy);
    float w00 = (1.f - fz) * (1.f - fy), w01 = (1.f - fz) * fy;
    float w10 = fz * (1.f - fy), w11 = fz * fy;
    int bz0 = (z0 - zb) << 8, bz1 = (z1 - zb) << 8;
    int by0 = y0 << 4, by1 = y1 << 4;
    plane[e] = w00 * hs[bz0 + by0 + x] + w01 * hs[bz0 + by1 + x]
             + w10 * hs[bz1 + by0 + x] + w11 * hs[bz1 + by1 + x];
  }
  __syncthreads();

  const float Aa = abS[0], Bb = abS[1];
  const size_t gbase = ((size_t)(n * 9 + c) * 64 + od_base) * 1024;  // f4 units
  const f4* v4 = (const f4*)vol;
  f4* o4 = (f4*)outp;

  // pass 2: x-lerp + stream, 2 batches x 8 f4 per thread, loads issued early
#pragma unroll
  for (int b = 0; b < 2; ++b) {
    f4 vv[8]; f4 pp[8]; size_t gg[8];
#pragma unroll
    for (int i = 0; i < 8; ++i) {
      int u = tid + (b * 8 + i) * 512;
      gg[i] = gbase + (size_t)u;
      vv[i] = v4[gg[i]];            // 8 independent loads in flight
    }
#pragma unroll
    for (int i = 0; i < 8; ++i) {
      int u = tid + (b * 8 + i) * 512;
      int owq = u & 15, base = (u >> 4) << 4;
      int xa = owq ? owq - 1 : 0;
      int xc = owq < 15 ? owq + 1 : 15;
      float A = plane[base + xa], B = plane[base + owq], C = plane[base + xc];
      pp[i].x = A + 0.625f * (B - A);
      pp[i].y = A + 0.875f * (B - A);
      pp[i].z = B + 0.125f * (C - B);
      pp[i].w = B + 0.375f * (C - B);
    }
#pragma unroll
    for (int i = 0; i < 8; ++i) {
      f4 oo;
      oo.x = vv[i].x + sc * fmaf(Aa, pp[i].x, Bb);
      oo.y = vv[i].y + sc * fmaf(Aa, pp[i].y, Bb);
      oo.z = vv[i].z + sc * fmaf(Aa, pp[i].z, Bb);
      oo.w = vv[i].w + sc * fmaf(Aa, pp[i].w, Bb);
      o4[gg[i]] = oo;
    }
  }
}

// ---------------------------------------------------------------------------
extern "C" void kernel_launch(void* const* d_in, const int* in_sizes, int n_in,
                              void* d_out, int out_size, void* d_ws, size_t ws_size,
                              hipStream_t stream) {
  (void)in_sizes; (void)n_in; (void)out_size; (void)ws_size;
  const float* obj  = (const float*)d_in[0];
  const int*   eidx = (const int*)d_in[1];
  const float* vol  = (const float*)d_in[2];
  const float* W1   = (const float*)d_in[3];
  const float* as1  = (const float*)d_in[4];
  const float* ad1  = (const float*)d_in[5];
  const float* b1   = (const float*)d_in[6];
  const float* W2   = (const float*)d_in[7];
  const float* as2  = (const float*)d_in[8];
  const float* ad2  = (const float*)d_in[9];
  const float* b2   = (const float*)d_in[10];
  const float* lng  = (const float*)d_in[11];
  const float* lnb  = (const float*)d_in[12];
  const float* scp  = (const float*)d_in[13];
  const float* linW = (const float*)d_in[14];
  const float* linb = (const float*)d_in[15];
  const float* ct1W = (const float*)d_in[16];
  const float* ct1b = (const float*)d_in[17];
  const float* ct2W = (const float*)d_in[18];
  const float* ct2b = (const float*)d_in[19];
  const float* bng  = (const float*)d_in[20];
  const float* bnb  = (const float*)d_in[21];

  float* ws   = (float*)d_ws;
  float* xlg  = ws;                  // 432 f
  float* hct1 = ws + 432;            // 393216 f
  float* h2   = ws + 393648;         // 1769472 f
  float* psum = ws + 2163120;        // 432 f
  float* pssq = ws + 2163552;        // 432 f  (~8.66 MB)

  float* out = (float*)d_out;

  kA<<<1, 512, 0, stream>>>(obj, eidx, W1, as1, ad1, b1, W2, as2, ad2, b2,
                            lng, lnb, xlg);
  kBC<<<dim3(16, 48), 256, 0, stream>>>(xlg, linW, linb, ct1W, ct1b, hct1);
  kD<<<dim3(9, 48), 256, 0, stream>>>(hct1, ct2W, ct2b, h2, psum, pssq);
  kF2<<<dim3(8, 9, 48), 512, 0, stream>>>(vol, h2, psum, pssq, bng, bnb, scp, out);
}